// Round 7
// baseline (591.884 us; speedup 1.0000x reference)
//
#include <hip/hip_runtime.h>

typedef unsigned short ushort_t;
typedef __bf16 bf16x8 __attribute__((ext_vector_type(8)));
typedef float f32x4 __attribute__((ext_vector_type(4)));

__device__ __forceinline__ ushort_t f2bf(float f) {
  unsigned u = __float_as_uint(f);
  u += 0x7fff + ((u >> 16) & 1);
  return (ushort_t)(u >> 16);
}

// ---------------- weight fp32 -> bf16, pack qk bias, zero stats2 ----------------
__global__ __launch_bounds__(256) void cvt_weights(
    const float* __restrict__ wq, const float* __restrict__ wk,
    const float* __restrict__ wv, const float* __restrict__ wo,
    const float* __restrict__ bq, const float* __restrict__ bk,
    ushort_t* __restrict__ dst, float* __restrict__ qkbias,
    float* __restrict__ stats2) {
  int b = blockIdx.x, t = threadIdx.x;
  if (b < 1024) {
    int i = b * 256 + t;
    dst[i]          = f2bf(wq[i]);
    dst[262144 + i] = f2bf(wk[i]);
    dst[524288 + i] = f2bf(wv[i]);
    dst[786432 + i] = f2bf(wo[i]);
  } else if (b < 1028) {
    int j = (b - 1024) * 256 + t;  // 0..1023
    qkbias[j] = (j < 512) ? bq[j] : bk[j - 512];
  } else {
    if (t < 128) stats2[t] = 0.f;
  }
}

// ---------------- zero the rowsum accumulator ----------------
__global__ __launch_bounds__(256) void zero_f32(float* __restrict__ p) {
  p[blockIdx.x * 256 + threadIdx.x] = 0.f;
}

// ---------------- group norm partial stats: 4 blocks per (b,g) ----------------
__global__ __launch_bounds__(256) void gn_stats_partial(const float* __restrict__ x,
                                                        float* __restrict__ stats2) {
  int bg = blockIdx.x >> 2, q = blockIdx.x & 3;
  const float4* p = (const float4*)(x + (size_t)bg * 65536 + q * 16384);
  float s = 0.f, ss = 0.f;
  for (int i = threadIdx.x; i < 4096; i += 256) {
    float4 v = p[i];
    s += v.x + v.y + v.z + v.w;
    ss += v.x * v.x + v.y * v.y + v.z * v.z + v.w * v.w;
  }
  for (int off = 32; off; off >>= 1) {
    s += __shfl_xor(s, off, 64);
    ss += __shfl_xor(ss, off, 64);
  }
  __shared__ float sh[8];
  int wave = threadIdx.x >> 6, lane = threadIdx.x & 63;
  if (lane == 0) { sh[wave] = s; sh[4 + wave] = ss; }
  __syncthreads();
  if (threadIdx.x == 0) {
    atomicAdd(&stats2[bg * 2], sh[0] + sh[1] + sh[2] + sh[3]);
    atomicAdd(&stats2[bg * 2 + 1], sh[4] + sh[5] + sh[6] + sh[7]);
  }
}

__global__ __launch_bounds__(64) void gn_finalize(const float* __restrict__ stats2,
                                                  float* __restrict__ stats) {
  int t = threadIdx.x;  // 64 groups total (2 batches x 32)
  float s = stats2[t * 2], ss = stats2[t * 2 + 1];
  float mean = s * (1.f / 65536.f);
  float var = ss * (1.f / 65536.f) - mean * mean;
  stats[t * 2] = mean;
  stats[t * 2 + 1] = rsqrtf(var + 1e-6f);
}

// ---------------- GN apply + transpose: x (b,c,n) -> hnT (b,n,c) bf16 ----------------
__global__ __launch_bounds__(256) void gn_apply(
    const float* __restrict__ x, const float* __restrict__ gamma,
    const float* __restrict__ beta, const float* __restrict__ stats,
    ushort_t* __restrict__ hnT) {
  __shared__ float T[32][33];
  int i0 = blockIdx.x * 32, c0 = blockIdx.y * 32, b = blockIdx.z;
  int tx = threadIdx.x, ty = threadIdx.y;  // (32,8)
#pragma unroll
  for (int k = 0; k < 4; k++) {
    int cl = ty + k * 8;
    int c = c0 + cl;
    int bg = (b * 32 + (c >> 4)) * 2;
    float mean = stats[bg], rstd = stats[bg + 1];
    float v = x[((size_t)(b * 512 + c)) * 4096 + i0 + tx];
    T[cl][tx] = (v - mean) * rstd * gamma[c] + beta[c];
  }
  __syncthreads();
#pragma unroll
  for (int k = 0; k < 4; k++) {
    int il = ty + k * 8;
    hnT[((size_t)b * 4096 + i0 + il) * 512 + c0 + tx] = f2bf(T[tx][il]);
  }
}

// ---------------- C = A * B^T GEMM, 128 x BN tile, bf16 in / fp32 acc ----------------
// VGPR-staged single-barrier double-buffered pipeline (AITER-style): global
// loads go to VGPRs (they survive s_barrier; only lgkmcnt drains), ds_write of
// tile k+1 waits vmcnt(N!=0) on loads issued one full iteration earlier.
// Invariant at loop top: LDS[p] = tile k, regs = tile k+1.
// B rows staged with in-window permutation slot s -> (s&15)*4+(s>>4) so lane
// l16's NI=4 accumulators are 4 consecutive output columns (packed stores).
template <int BN>
__global__ __launch_bounds__(256) void gemm_abt(
    const ushort_t* __restrict__ A, long long sA, int lda,
    const ushort_t* __restrict__ B, long long sB, int ldb,
    int K, int N, int ldc,
    ushort_t* __restrict__ outB, long long sC,
    const float* __restrict__ bias, int bias_mode, float scale,
    float* __restrict__ outF, const float* __restrict__ resid,
    float* __restrict__ rowsum, const float* __restrict__ colscale, int swiz) {
  constexpr int CPW = (8 + BN / 16) / 4;   // staging chunks per wave
  constexpr int RS = 40;                   // LDS row stride (halfwords, 80B = 5 banks)
  constexpr int SBH = (128 + BN) * RS;     // halfwords per buffer
  constexpr int MI = (BN == 128) ? 4 : 2;
  constexpr int NI = 4;
  __shared__ __align__(16) ushort_t Ls[2][SBH];

  int bx = blockIdx.x, by = blockIdx.y, bz = blockIdx.z;
  if (swiz) {
    unsigned nx = gridDim.x, ny = gridDim.y;
    unsigned id = (blockIdx.z * ny + blockIdx.y) * nx + blockIdx.x;
    unsigned pb8 = (nx * ny) >> 3;   // per-batch blocks / 8
    unsigned c = id & 7, j = id >> 3;
    bz = j / pb8;
    unsigned jb = j - bz * pb8;
    unsigned jy = jb / nx;
    by = c * (ny >> 3) + jy;
    bx = jb - jy * nx;
  }

  int m0 = by * 128, n0 = bx * BN;
  int t = threadIdx.x;
  int lane = t & 63;
  int quad = lane >> 4, l16 = lane & 15;
  int wave = t >> 6;
  int wm = (BN == 128) ? (wave >> 1) * 64 : wave * 32;
  int wn = (BN == 128) ? (wave & 1) * 64 : 0;

  f32x4 acc[MI][NI];
#pragma unroll
  for (int i = 0; i < MI; i++)
#pragma unroll
    for (int j = 0; j < NI; j++)
#pragma unroll
      for (int r = 0; r < 4; r++) acc[i][j][r] = 0.f;

  // staging map: chunk = 16 rows x 32 cols; thread covers row lane>>2, 16B seg lane&3
  const ushort_t* gp[CPW];
  int lofs[CPW];  // halfword index within one LDS buffer
  int crow = lane >> 2, skoff = (lane & 3) * 8;
#pragma unroll
  for (int i = 0; i < CPW; i++) {
    int c = wave * CPW + i;
    if (c < 8) {
      gp[i] = A + (size_t)bz * sA + (size_t)(m0 + c * 16 + crow) * lda + skoff;
      lofs[i] = (c * 16 + crow) * RS + skoff;
    } else {
      int slot = (c - 8) * 16 + crow;  // B slot in [0, BN)
      int arow = (slot & ~63) + ((slot & 15) * 4) + ((slot & 63) >> 4);
      gp[i] = B + (size_t)bz * sB + (size_t)(n0 + arow) * ldb + skoff;
      lofs[i] = (128 + slot) * RS + skoff;
    }
  }

  // prologue: tile0 -> regs -> LDS[0]; tile1 -> regs
  uint4 st[CPW];
#pragma unroll
  for (int i = 0; i < CPW; i++) st[i] = *(const uint4*)(gp[i]);
#pragma unroll
  for (int i = 0; i < CPW; i++) *(uint4*)&Ls[0][lofs[i]] = st[i];
#pragma unroll
  for (int i = 0; i < CPW; i++) st[i] = *(const uint4*)(gp[i] + 32);
  __syncthreads();

  for (int k0 = 0; k0 < K; k0 += 32) {
    int p = (k0 >> 5) & 1;
    if (k0 + 32 < K) {
      // write tile k+1 into other buffer (vmcnt waits only on iter-old loads)
#pragma unroll
      for (int i = 0; i < CPW; i++) *(uint4*)&Ls[p ^ 1][lofs[i]] = st[i];
      if (k0 + 64 < K) {
#pragma unroll
        for (int i = 0; i < CPW; i++) st[i] = *(const uint4*)(gp[i] + k0 + 64);
      }
    }
    bf16x8 af[MI], bfr[NI];
#pragma unroll
    for (int i = 0; i < MI; i++)
      af[i] = *(const bf16x8*)&Ls[p][(wm + i * 16 + l16) * RS + quad * 8];
#pragma unroll
    for (int j = 0; j < NI; j++)
      bfr[j] = *(const bf16x8*)&Ls[p][(128 + wn + j * 16 + l16) * RS + quad * 8];
#pragma unroll
    for (int mi = 0; mi < MI; mi++)
#pragma unroll
      for (int ni = 0; ni < NI; ni++)
        acc[mi][ni] = __builtin_amdgcn_mfma_f32_16x16x32_bf16(af[mi], bfr[ni], acc[mi][ni], 0, 0, 0);
    __syncthreads();  // my reads of p done; others' writes of p^1 done
  }

  // epilogue: lane l16, tile ni = column n0 + wn + l16*4 + ni (4 consecutive)
  size_t cbase = (size_t)bz * sC;
  int gnb = n0 + wn + l16 * 4;
  float cs4[4] = {1.f, 1.f, 1.f, 1.f};
  if (colscale) {
    float4 c4 = *(const float4*)&colscale[(size_t)bz * N + gnb];
    cs4[0] = 1.f / c4.x; cs4[1] = 1.f / c4.y; cs4[2] = 1.f / c4.z; cs4[3] = 1.f / c4.w;
  }
  float b4[4] = {0.f, 0.f, 0.f, 0.f};
  if (bias_mode == 2) {
    float4 t4 = *(const float4*)&bias[gnb];
    b4[0] = t4.x; b4[1] = t4.y; b4[2] = t4.z; b4[3] = t4.w;
  }
#pragma unroll
  for (int mi = 0; mi < MI; mi++) {
#pragma unroll
    for (int r = 0; r < 4; r++) {
      int m = m0 + wm + mi * 16 + quad * 4 + r;
      float rbias = (bias_mode == 1) ? bias[m] : 0.f;
      float v4[4];
      float rs = 0.f;
#pragma unroll
      for (int ni = 0; ni < NI; ni++) {
        float val = acc[mi][ni][r];
        if (colscale) val *= cs4[ni];
        val += (bias_mode == 2) ? b4[ni] : rbias;
        val *= scale;
        if (rowsum) { val = __expf(val); rs += val; }
        v4[ni] = val;
      }
      size_t idx = cbase + (size_t)m * ldc + gnb;
      if (outF) {
        float4 rv = *(const float4*)&resid[idx];
        float4 ov = make_float4(v4[0] + rv.x, v4[1] + rv.y, v4[2] + rv.z, v4[3] + rv.w);
        *(float4*)&outF[idx] = ov;
      } else {
        unsigned lo = (unsigned)f2bf(v4[0]) | ((unsigned)f2bf(v4[1]) << 16);
        unsigned hi = (unsigned)f2bf(v4[2]) | ((unsigned)f2bf(v4[3]) << 16);
        *(uint2*)&outB[idx] = make_uint2(lo, hi);
      }
      if (rowsum) {
        rs += __shfl_xor(rs, 1, 64);
        rs += __shfl_xor(rs, 2, 64);
        rs += __shfl_xor(rs, 4, 64);
        rs += __shfl_xor(rs, 8, 64);
        if (l16 == 0) atomicAdd(&rowsum[(size_t)bz * 4096 + m], rs);
      }
    }
  }
}

extern "C" void kernel_launch(void* const* d_in, const int* in_sizes, int n_in,
                              void* d_out, int out_size, void* d_ws, size_t ws_size,
                              hipStream_t stream) {
  const float* x     = (const float*)d_in[0];
  const float* gamma = (const float*)d_in[1];
  const float* beta  = (const float*)d_in[2];
  const float* wq    = (const float*)d_in[3];
  const float* bq    = (const float*)d_in[4];
  const float* wk    = (const float*)d_in[5];
  const float* bk    = (const float*)d_in[6];
  const float* wv    = (const float*)d_in[7];
  const float* bv    = (const float*)d_in[8];
  const float* wo    = (const float*)d_in[9];
  const float* bo    = (const float*)d_in[10];
  float* out = (float*)d_out;

  // workspace layout (bf16 elements)
  ushort_t* wb  = (ushort_t*)d_ws;     // [wq;wk] 1024x512, wv, wo
  ushort_t* wvb = wb + 524288;
  ushort_t* wob = wb + 786432;
  ushort_t* hnT = wb + 1048576;        // 2 x 4096 x 512
  ushort_t* qkT = hnT + 4194304;       // 2 x 4096 x 1024 (q cols 0-511, k cols 512-1023)
  ushort_t* vC  = qkT + 8388608;       // 2 x 512 x 4096
  ushort_t* OT  = vC + 4194304;        // 2 x 4096 x 512
  ushort_t* S   = OT + 4194304;        // 2 x 4096 x 4096 (holds P = exp(scale*S))
  float* fbuf   = (float*)(S + 33554432);
  float* stats  = fbuf;                // 128
  float* stats2 = fbuf + 128;          // 128
  float* qkbias = fbuf + 256;          // 1024
  float* l      = (float*)hnT;         // 2 x 4096 row sums (hnT dead after v-GEMM)

  const long long HS = 2097152;   // 4096*512 per batch
  const long long QS = 4194304;   // 4096*1024 per batch
  const long long SS = 16777216;  // 4096*4096 per batch
  const float scale = 0.044194173824159216f;  // 512^-0.5

  cvt_weights<<<dim3(1029), dim3(256), 0, stream>>>(wq, wk, wv, wo, bq, bk, wb, qkbias, stats2);
  gn_stats_partial<<<dim3(256), dim3(256), 0, stream>>>(x, stats2);
  gn_finalize<<<dim3(1), dim3(64), 0, stream>>>(stats2, stats);
  gn_apply<<<dim3(128, 16, 2), dim3(32, 8), 0, stream>>>(x, gamma, beta, stats, hnT);
  // qkT = hnT * [wq;wk]^T  (M=4096, N=1024, K=512), packed col bias
  gemm_abt<128><<<dim3(8, 32, 2), dim3(256), 0, stream>>>(
      hnT, HS, 512, wb, 0, 512, 512, 1024, 1024, qkT, QS, qkbias, 2, 1.f,
      nullptr, nullptr, nullptr, nullptr, 1);
  // vC = wv * hnT^T  (M=512, N=4096, K=512), row bias
  gemm_abt<64><<<dim3(64, 4, 2), dim3(256), 0, stream>>>(
      wvb, 0, 512, hnT, HS, 512, 512, 4096, 4096, vC, HS, bv, 1, 1.f,
      nullptr, nullptr, nullptr, nullptr, 0);
  // hnT dead; reuse as rowsum l
  zero_f32<<<dim3(32), dim3(256), 0, stream>>>(l);
  // P = exp(scale * q*k^T) with fused row sums (M=N=4096, K=512)
  gemm_abt<128><<<dim3(32, 32, 2), dim3(256), 0, stream>>>(
      qkT, QS, 1024, qkT + 512, QS, 1024, 512, 4096, 4096, S, SS, nullptr, 0, scale,
      nullptr, nullptr, l, nullptr, 1);
  // OT = P * vC^T (M=4096, N=512, K=4096), unnormalized; swizzled for P-row L2 share
  gemm_abt<64><<<dim3(8, 32, 2), dim3(256), 0, stream>>>(
      S, SS, 4096, vC, HS, 4096, 4096, 512, 512, OT, HS, nullptr, 0, 1.f,
      nullptr, nullptr, nullptr, nullptr, 1);
  // y = wo * (OT/l)^T + bo + x (M=512, N=4096, K=512), fp32 out + residual
  gemm_abt<64><<<dim3(64, 4, 2), dim3(256), 0, stream>>>(
      wob, 0, 512, OT, HS, 512, 512, 4096, 4096, nullptr, HS, bo, 1, 1.f,
      out, x, nullptr, l, 0);
}

// Round 8
// 308.401 us; speedup vs baseline: 1.9192x; 1.9192x over previous
//
#include <hip/hip_runtime.h>

typedef unsigned short ushort_t;
typedef unsigned char uchar_t;
typedef __bf16 bf16x8 __attribute__((ext_vector_type(8)));
typedef float f32x4 __attribute__((ext_vector_type(4)));

__device__ __forceinline__ ushort_t f2bf(float f) {
  unsigned u = __float_as_uint(f);
  u += 0x7fff + ((u >> 16) & 1);
  return (ushort_t)(u >> 16);
}

__device__ __forceinline__ void gload16(const void* g, void* l) {
  __builtin_amdgcn_global_load_lds(
      (const __attribute__((address_space(1))) unsigned int*)g,
      (__attribute__((address_space(3))) unsigned int*)l, 16, 0, 0);
}

// ---------------- weight fp32 -> bf16, pack qk bias, zero stats2 ----------------
__global__ __launch_bounds__(256) void cvt_weights(
    const float* __restrict__ wq, const float* __restrict__ wk,
    const float* __restrict__ wv, const float* __restrict__ wo,
    const float* __restrict__ bq, const float* __restrict__ bk,
    ushort_t* __restrict__ dst, float* __restrict__ qkbias,
    float* __restrict__ stats2) {
  int b = blockIdx.x, t = threadIdx.x;
  if (b < 1024) {
    int i = b * 256 + t;
    dst[i]          = f2bf(wq[i]);
    dst[262144 + i] = f2bf(wk[i]);
    dst[524288 + i] = f2bf(wv[i]);
    dst[786432 + i] = f2bf(wo[i]);
  } else if (b < 1028) {
    int j = (b - 1024) * 256 + t;  // 0..1023
    qkbias[j] = (j < 512) ? bq[j] : bk[j - 512];
  } else {
    if (t < 128) stats2[t] = 0.f;
  }
}

// ---------------- zero the rowsum accumulator ----------------
__global__ __launch_bounds__(256) void zero_f32(float* __restrict__ p) {
  p[blockIdx.x * 256 + threadIdx.x] = 0.f;
}

// ---------------- group norm partial stats: 4 blocks per (b,g) ----------------
__global__ __launch_bounds__(256) void gn_stats_partial(const float* __restrict__ x,
                                                        float* __restrict__ stats2) {
  int bg = blockIdx.x >> 2, q = blockIdx.x & 3;
  const float4* p = (const float4*)(x + (size_t)bg * 65536 + q * 16384);
  float s = 0.f, ss = 0.f;
  for (int i = threadIdx.x; i < 4096; i += 256) {
    float4 v = p[i];
    s += v.x + v.y + v.z + v.w;
    ss += v.x * v.x + v.y * v.y + v.z * v.z + v.w * v.w;
  }
  for (int off = 32; off; off >>= 1) {
    s += __shfl_xor(s, off, 64);
    ss += __shfl_xor(ss, off, 64);
  }
  __shared__ float sh[8];
  int wave = threadIdx.x >> 6, lane = threadIdx.x & 63;
  if (lane == 0) { sh[wave] = s; sh[4 + wave] = ss; }
  __syncthreads();
  if (threadIdx.x == 0) {
    atomicAdd(&stats2[bg * 2], sh[0] + sh[1] + sh[2] + sh[3]);
    atomicAdd(&stats2[bg * 2 + 1], sh[4] + sh[5] + sh[6] + sh[7]);
  }
}

__global__ __launch_bounds__(64) void gn_finalize(const float* __restrict__ stats2,
                                                  float* __restrict__ stats) {
  int t = threadIdx.x;  // 64 groups total (2 batches x 32)
  float s = stats2[t * 2], ss = stats2[t * 2 + 1];
  float mean = s * (1.f / 65536.f);
  float var = ss * (1.f / 65536.f) - mean * mean;
  stats[t * 2] = mean;
  stats[t * 2 + 1] = rsqrtf(var + 1e-6f);
}

// ---------------- GN apply + transpose: x (b,c,n) -> hnT (b,n,c) bf16 ----------------
__global__ __launch_bounds__(256) void gn_apply(
    const float* __restrict__ x, const float* __restrict__ gamma,
    const float* __restrict__ beta, const float* __restrict__ stats,
    ushort_t* __restrict__ hnT) {
  __shared__ float T[32][33];
  int i0 = blockIdx.x * 32, c0 = blockIdx.y * 32, b = blockIdx.z;
  int tx = threadIdx.x, ty = threadIdx.y;  // (32,8)
#pragma unroll
  for (int k = 0; k < 4; k++) {
    int cl = ty + k * 8;
    int c = c0 + cl;
    int bg = (b * 32 + (c >> 4)) * 2;
    float mean = stats[bg], rstd = stats[bg + 1];
    float v = x[((size_t)(b * 512 + c)) * 4096 + i0 + tx];
    T[cl][tx] = (v - mean) * rstd * gamma[c] + beta[c];
  }
  __syncthreads();
#pragma unroll
  for (int k = 0; k < 4; k++) {
    int il = ty + k * 8;
    hnT[((size_t)b * 4096 + i0 + il) * 512 + c0 + tx] = f2bf(T[tx][il]);
  }
}

// ---------------- C = A * B^T GEMM, 128 x BN tile, bf16 in / fp32 acc ----------------
// Round-5 engine: single-barrier double-buffered global_load_lds DMA staging,
// B rows staged with in-window permutation slot s -> (s&15)*4+(s>>4) so lane
// l16's NI=4 accumulators are 4 consecutive output columns (packed stores).
// omode: 0 = bf16 out, 1 = fp32 + residual, 2 = fp8 e4m3 out (P/V path).
template <int BN>
__global__ __launch_bounds__(256) void gemm_abt(
    const ushort_t* __restrict__ A, long long sA, int lda,
    const ushort_t* __restrict__ B, long long sB, int ldb,
    int K, int N, int ldc,
    ushort_t* __restrict__ outB, long long sC,
    const float* __restrict__ bias, int bias_mode, float scale,
    float* __restrict__ outF, const float* __restrict__ resid,
    float* __restrict__ rowsum, const float* __restrict__ colscale,
    int swiz, int omode) {
  constexpr int CPW = (8 + BN / 16) / 4;   // staging chunks per wave
  constexpr int SB = (128 + BN) * 32;      // halfwords per LDS buffer
  constexpr int MI = (BN == 128) ? 4 : 2;
  constexpr int NI = 4;
  __shared__ __align__(16) ushort_t Ls[2][SB];

  int bx = blockIdx.x, by = blockIdx.y, bz = blockIdx.z;
  if (swiz) {
    unsigned nx = gridDim.x, ny = gridDim.y;
    unsigned id = (blockIdx.z * ny + blockIdx.y) * nx + blockIdx.x;
    unsigned pb8 = (nx * ny) >> 3;   // per-batch blocks / 8
    unsigned c = id & 7, j = id >> 3;
    bz = j / pb8;
    unsigned jb = j - bz * pb8;
    unsigned jy = jb / nx;
    by = c * (ny >> 3) + jy;
    bx = jb - jy * nx;
  }

  int m0 = by * 128, n0 = bx * BN;
  int t = threadIdx.x;
  int lane = t & 63;
  int quad = lane >> 4, l16 = lane & 15;
  int wave = t >> 6;
  int wm = (BN == 128) ? (wave >> 1) * 64 : wave * 32;
  int wn = (BN == 128) ? (wave & 1) * 64 : 0;

  f32x4 acc[MI][NI];
#pragma unroll
  for (int i = 0; i < MI; i++)
#pragma unroll
    for (int j = 0; j < NI; j++)
#pragma unroll
      for (int r = 0; r < 4; r++) acc[i][j][r] = 0.f;

  // staging map: chunk = 16 rows x 32 cols bf16; lane covers row lane>>2, 16B seg lane&3
  const ushort_t* gp[CPW];
  int lofs[CPW];  // byte offset within one LDS buffer
  int crow = lane >> 2, skoff = (lane & 3) * 8;
#pragma unroll
  for (int i = 0; i < CPW; i++) {
    int c = wave * CPW + i;
    if (c < 8) {
      gp[i] = A + (size_t)bz * sA + (size_t)(m0 + c * 16 + crow) * lda + skoff;
      lofs[i] = c * 1024 + lane * 16;
    } else {
      int slot = (c - 8) * 16 + crow;  // B slot in [0, BN)
      int arow = (slot & ~63) + ((slot & 15) * 4) + ((slot & 63) >> 4);
      gp[i] = B + (size_t)bz * sB + (size_t)(n0 + arow) * ldb + skoff;
      lofs[i] = 8192 + (c - 8) * 1024 + lane * 16;
    }
  }
  char* lbase = (char*)&Ls[0][0];

  // prologue: tile 0 -> buffer 0
#pragma unroll
  for (int i = 0; i < CPW; i++) gload16(gp[i], lbase + lofs[i]);

  for (int k0 = 0; k0 < K; k0 += 32) {
    int p = (k0 >> 5) & 1;
    __syncthreads();
    if (k0 + 32 < K) {
      int pofs = (p ^ 1) * (SB * 2);
#pragma unroll
      for (int i = 0; i < CPW; i++) gload16(gp[i] + k0 + 32, lbase + pofs + lofs[i]);
    }
    bf16x8 af[MI], bfr[NI];
#pragma unroll
    for (int i = 0; i < MI; i++)
      af[i] = *(const bf16x8*)&Ls[p][(wm + i * 16 + l16) * 32 + quad * 8];
#pragma unroll
    for (int j = 0; j < NI; j++)
      bfr[j] = *(const bf16x8*)&Ls[p][4096 + (wn + j * 16 + l16) * 32 + quad * 8];
#pragma unroll
    for (int mi = 0; mi < MI; mi++)
#pragma unroll
      for (int ni = 0; ni < NI; ni++)
        acc[mi][ni] = __builtin_amdgcn_mfma_f32_16x16x32_bf16(af[mi], bfr[ni], acc[mi][ni], 0, 0, 0);
  }

  // epilogue: lane l16, tile ni = column n0 + wn + l16*4 + ni (4 consecutive)
  size_t cbase = (size_t)bz * sC;
  int gnb = n0 + wn + l16 * 4;
  float cs4[4] = {1.f, 1.f, 1.f, 1.f};
  if (colscale) {
    float4 c4 = *(const float4*)&colscale[(size_t)bz * N + gnb];
    cs4[0] = 1.f / c4.x; cs4[1] = 1.f / c4.y; cs4[2] = 1.f / c4.z; cs4[3] = 1.f / c4.w;
  }
  float b4[4] = {0.f, 0.f, 0.f, 0.f};
  if (bias_mode == 2) {
    float4 t4 = *(const float4*)&bias[gnb];
    b4[0] = t4.x; b4[1] = t4.y; b4[2] = t4.z; b4[3] = t4.w;
  }
#pragma unroll
  for (int mi = 0; mi < MI; mi++) {
#pragma unroll
    for (int r = 0; r < 4; r++) {
      int m = m0 + wm + mi * 16 + quad * 4 + r;
      float rbias = (bias_mode == 1) ? bias[m] : 0.f;
      float v4[4];
      float rs = 0.f;
#pragma unroll
      for (int ni = 0; ni < NI; ni++) {
        float val = acc[mi][ni][r];
        if (colscale) val *= cs4[ni];
        val += (bias_mode == 2) ? b4[ni] : rbias;
        val *= scale;
        if (rowsum) {
          val = __expf(val);
          if (omode == 2) val *= 0.0625f;  // keep exp within fp8 range; l matches
          rs += val;
        }
        v4[ni] = val;
      }
      size_t idx = cbase + (size_t)m * ldc + gnb;
      if (omode == 1) {
        float4 rv = *(const float4*)&resid[idx];
        float4 ov = make_float4(v4[0] + rv.x, v4[1] + rv.y, v4[2] + rv.z, v4[3] + rv.w);
        *(float4*)&outF[idx] = ov;
      } else if (omode == 2) {
        unsigned w = __builtin_amdgcn_cvt_pk_fp8_f32(v4[0], v4[1], 0u, false);
        w = __builtin_amdgcn_cvt_pk_fp8_f32(v4[2], v4[3], w, true);
        *(unsigned*)&((uchar_t*)outB)[idx] = w;
      } else {
        unsigned lo = (unsigned)f2bf(v4[0]) | ((unsigned)f2bf(v4[1]) << 16);
        unsigned hi = (unsigned)f2bf(v4[2]) | ((unsigned)f2bf(v4[3]) << 16);
        *(uint2*)&outB[idx] = make_uint2(lo, hi);
      }
      if (rowsum) {
        rs += __shfl_xor(rs, 1, 64);
        rs += __shfl_xor(rs, 2, 64);
        rs += __shfl_xor(rs, 4, 64);
        rs += __shfl_xor(rs, 8, 64);
        if (l16 == 0) atomicAdd(&rowsum[(size_t)bz * 4096 + m], rs);
      }
    }
  }
}

// ---------------- OT = P(fp8) * V(fp8)^T, 128x64 tile, BK=64, bf16 out --------
// Same DMA engine; fp8 halves bytes/iter and halves iteration count (64 vs 128).
__global__ __launch_bounds__(256) void gemm_o_fp8(
    const uchar_t* __restrict__ P, long long sA,   // lda = 4096 bytes
    const uchar_t* __restrict__ V, long long sB,   // ldb = 4096 bytes
    int K, ushort_t* __restrict__ OT, long long sC, int ldc) {
  __shared__ __align__(16) uchar_t Ls[2][12288];  // (128+64) rows x 64 B

  unsigned nx = gridDim.x, ny = gridDim.y;
  unsigned id = (blockIdx.z * ny + blockIdx.y) * nx + blockIdx.x;
  unsigned pb8 = (nx * ny) >> 3;
  unsigned c8 = id & 7, j = id >> 3;
  int bz = j / pb8;
  unsigned jb = j - bz * pb8;
  unsigned jy = jb / nx;
  int by = c8 * (ny >> 3) + jy;
  int bx = jb - jy * nx;

  int m0 = by * 128, n0 = bx * 64;
  int t = threadIdx.x, lane = t & 63, quad = lane >> 4, l16 = lane & 15, wave = t >> 6;
  int wm = wave * 32;

  f32x4 acc[2][4];
#pragma unroll
  for (int i = 0; i < 2; i++)
#pragma unroll
    for (int jj = 0; jj < 4; jj++)
#pragma unroll
      for (int r = 0; r < 4; r++) acc[i][jj][r] = 0.f;

  // staging: 12 chunks (16 rows x 64 B); wave w covers chunks 3w..3w+2
  const uchar_t* gp[3];
  int lofs[3];
  int crow = lane >> 2, skoff = (lane & 3) * 16;
#pragma unroll
  for (int i = 0; i < 3; i++) {
    int c = wave * 3 + i;
    if (c < 8) {
      gp[i] = P + (size_t)bz * sA + (size_t)(m0 + c * 16 + crow) * 4096 + skoff;
      lofs[i] = c * 1024 + lane * 16;
    } else {
      int slot = (c - 8) * 16 + crow;           // 0..63
      int arow = (slot & 15) * 4 + (slot >> 4); // packed-epilogue permutation
      gp[i] = V + (size_t)bz * sB + (size_t)(n0 + arow) * 4096 + skoff;
      lofs[i] = 8192 + (c - 8) * 1024 + lane * 16;
    }
  }
  char* lbase = (char*)&Ls[0][0];
#pragma unroll
  for (int i = 0; i < 3; i++) gload16(gp[i], lbase + lofs[i]);

  for (int k0 = 0; k0 < K; k0 += 64) {
    int p = (k0 >> 6) & 1;
    __syncthreads();
    if (k0 + 64 < K) {
      int pofs = (p ^ 1) * 12288;
#pragma unroll
      for (int i = 0; i < 3; i++) gload16(gp[i] + k0 + 64, lbase + pofs + lofs[i]);
    }
    const uchar_t* Lp = &Ls[p][0];
#pragma unroll
    for (int sub = 0; sub < 2; sub++) {
      long af[2], bfv[4];
#pragma unroll
      for (int i = 0; i < 2; i++)
        af[i] = *(const long*)&Lp[(wm + i * 16 + l16) * 64 + sub * 32 + quad * 8];
#pragma unroll
      for (int jj = 0; jj < 4; jj++)
        bfv[jj] = *(const long*)&Lp[(128 + jj * 16 + l16) * 64 + sub * 32 + quad * 8];
#pragma unroll
      for (int mi = 0; mi < 2; mi++)
#pragma unroll
        for (int ni = 0; ni < 4; ni++)
          acc[mi][ni] = __builtin_amdgcn_mfma_f32_16x16x32_fp8_fp8(af[mi], bfv[ni], acc[mi][ni], 0, 0, 0);
    }
  }

  // epilogue: packed bf16 stores; column = n0 + l16*4 + ni
  size_t cbase = (size_t)bz * sC;
  int gnb = n0 + l16 * 4;
#pragma unroll
  for (int mi = 0; mi < 2; mi++) {
#pragma unroll
    for (int r = 0; r < 4; r++) {
      int m = m0 + wm + mi * 16 + quad * 4 + r;
      unsigned lo = (unsigned)f2bf(acc[mi][0][r]) | ((unsigned)f2bf(acc[mi][1][r]) << 16);
      unsigned hi = (unsigned)f2bf(acc[mi][2][r]) | ((unsigned)f2bf(acc[mi][3][r]) << 16);
      *(uint2*)&OT[cbase + (size_t)m * ldc + gnb] = make_uint2(lo, hi);
    }
  }
}

extern "C" void kernel_launch(void* const* d_in, const int* in_sizes, int n_in,
                              void* d_out, int out_size, void* d_ws, size_t ws_size,
                              hipStream_t stream) {
  const float* x     = (const float*)d_in[0];
  const float* gamma = (const float*)d_in[1];
  const float* beta  = (const float*)d_in[2];
  const float* wq    = (const float*)d_in[3];
  const float* bq    = (const float*)d_in[4];
  const float* wk    = (const float*)d_in[5];
  const float* bk    = (const float*)d_in[6];
  const float* wv    = (const float*)d_in[7];
  const float* bv    = (const float*)d_in[8];
  const float* wo    = (const float*)d_in[9];
  const float* bo    = (const float*)d_in[10];
  float* out = (float*)d_out;

  // workspace layout
  ushort_t* wb  = (ushort_t*)d_ws;     // [wq;wk] 1024x512, wv, wo (bf16)
  ushort_t* wvb = wb + 524288;
  ushort_t* wob = wb + 786432;
  ushort_t* hnT = wb + 1048576;        // 2 x 4096 x 512 bf16
  ushort_t* qkT = hnT + 4194304;       // 2 x 4096 x 1024 bf16
  uchar_t*  vC8 = (uchar_t*)(qkT + 8388608);  // 2 x 512 x 4096 fp8
  ushort_t* OT  = (ushort_t*)(vC8 + 4194304); // 2 x 4096 x 512 bf16
  uchar_t*  S8  = (uchar_t*)(OT + 4194304);   // 2 x 4096 x 4096 fp8 (P' = exp/16)
  float* fbuf   = (float*)(S8 + 33554432);
  float* stats  = fbuf;                // 128
  float* stats2 = fbuf + 128;          // 128
  float* qkbias = fbuf + 256;          // 1024
  float* l      = (float*)hnT;         // 2 x 4096 row sums (hnT dead after v-GEMM)

  const long long HS = 2097152;   // 4096*512 per batch (elems; == bytes for fp8 v)
  const long long QS = 4194304;   // 4096*1024 per batch
  const long long SS = 16777216;  // 4096*4096 per batch (bytes, fp8)
  const float scale = 0.044194173824159216f;  // 512^-0.5

  cvt_weights<<<dim3(1029), dim3(256), 0, stream>>>(wq, wk, wv, wo, bq, bk, wb, qkbias, stats2);
  gn_stats_partial<<<dim3(256), dim3(256), 0, stream>>>(x, stats2);
  gn_finalize<<<dim3(1), dim3(64), 0, stream>>>(stats2, stats);
  gn_apply<<<dim3(128, 16, 2), dim3(32, 8), 0, stream>>>(x, gamma, beta, stats, hnT);
  // qkT = hnT * [wq;wk]^T  (M=4096, N=1024, K=512), packed col bias, bf16 out
  gemm_abt<128><<<dim3(8, 32, 2), dim3(256), 0, stream>>>(
      hnT, HS, 512, wb, 0, 512, 512, 1024, 1024, qkT, QS, qkbias, 2, 1.f,
      nullptr, nullptr, nullptr, nullptr, 1, 0);
  // vC8 = wv * hnT^T  (M=512, N=4096, K=512), row bias, fp8 out
  gemm_abt<64><<<dim3(64, 4, 2), dim3(256), 0, stream>>>(
      wvb, 0, 512, hnT, HS, 512, 512, 4096, 4096, (ushort_t*)vC8, HS, bv, 1, 1.f,
      nullptr, nullptr, nullptr, nullptr, 0, 2);
  // hnT dead; reuse as rowsum l
  zero_f32<<<dim3(32), dim3(256), 0, stream>>>(l);
  // P' = exp(scale * q*k^T)/16 fp8, fused row sums of P' (M=N=4096, K=512)
  gemm_abt<128><<<dim3(32, 32, 2), dim3(256), 0, stream>>>(
      qkT, QS, 1024, qkT + 512, QS, 1024, 512, 4096, 4096, (ushort_t*)S8, SS, nullptr, 0, scale,
      nullptr, nullptr, l, nullptr, 1, 2);
  // OT = P' * vC8^T (fp8 MFMA, M=4096, N=512, K=4096), bf16 out, swizzled
  gemm_o_fp8<<<dim3(8, 32, 2), dim3(256), 0, stream>>>(
      S8, SS, vC8, HS, 4096, OT, HS, 512);
  // y = wo * (OT/l')^T + bo + x  (l' = sum P' matches /16 scaling), fp32 + residual
  gemm_abt<64><<<dim3(64, 4, 2), dim3(256), 0, stream>>>(
      wob, 0, 512, OT, HS, 512, 512, 4096, 4096, nullptr, HS, bo, 1, 1.f,
      out, x, nullptr, l, 0, 1);
}

// Round 9
// 240.728 us; speedup vs baseline: 2.4587x; 1.2811x over previous
//
#include <hip/hip_runtime.h>

typedef unsigned short ushort_t;
typedef unsigned char uchar_t;
typedef __bf16 bf16x8 __attribute__((ext_vector_type(8)));
typedef float f32x4 __attribute__((ext_vector_type(4)));

__device__ __forceinline__ ushort_t f2bf(float f) {
  unsigned u = __float_as_uint(f);
  u += 0x7fff + ((u >> 16) & 1);
  return (ushort_t)(u >> 16);
}

__device__ __forceinline__ void gload16(const void* g, void* l) {
  __builtin_amdgcn_global_load_lds(
      (const __attribute__((address_space(1))) unsigned int*)g,
      (__attribute__((address_space(3))) unsigned int*)l, 16, 0, 0);
}

// ---------------- weight fp32 -> bf16, pack qk bias, zero stats2 ----------------
__global__ __launch_bounds__(256) void cvt_weights(
    const float* __restrict__ wq, const float* __restrict__ wk,
    const float* __restrict__ wv, const float* __restrict__ wo,
    const float* __restrict__ bq, const float* __restrict__ bk,
    ushort_t* __restrict__ dst, float* __restrict__ qkbias,
    float* __restrict__ stats2) {
  int b = blockIdx.x, t = threadIdx.x;
  if (b < 1024) {
    int i = b * 256 + t;
    dst[i]          = f2bf(wq[i]);
    dst[262144 + i] = f2bf(wk[i]);
    dst[524288 + i] = f2bf(wv[i]);
    dst[786432 + i] = f2bf(wo[i]);
  } else if (b < 1028) {
    int j = (b - 1024) * 256 + t;  // 0..1023
    qkbias[j] = (j < 512) ? bq[j] : bk[j - 512];
  } else {
    if (t < 128) stats2[t] = 0.f;
  }
}

// ---------------- zero the rowsum accumulator ----------------
__global__ __launch_bounds__(256) void zero_f32(float* __restrict__ p) {
  p[blockIdx.x * 256 + threadIdx.x] = 0.f;
}

// ---------------- group norm partial stats: 4 blocks per (b,g) ----------------
__global__ __launch_bounds__(256) void gn_stats_partial(const float* __restrict__ x,
                                                        float* __restrict__ stats2) {
  int bg = blockIdx.x >> 2, q = blockIdx.x & 3;
  const float4* p = (const float4*)(x + (size_t)bg * 65536 + q * 16384);
  float s = 0.f, ss = 0.f;
  for (int i = threadIdx.x; i < 4096; i += 256) {
    float4 v = p[i];
    s += v.x + v.y + v.z + v.w;
    ss += v.x * v.x + v.y * v.y + v.z * v.z + v.w * v.w;
  }
  for (int off = 32; off; off >>= 1) {
    s += __shfl_xor(s, off, 64);
    ss += __shfl_xor(ss, off, 64);
  }
  __shared__ float sh[8];
  int wave = threadIdx.x >> 6, lane = threadIdx.x & 63;
  if (lane == 0) { sh[wave] = s; sh[4 + wave] = ss; }
  __syncthreads();
  if (threadIdx.x == 0) {
    atomicAdd(&stats2[bg * 2], sh[0] + sh[1] + sh[2] + sh[3]);
    atomicAdd(&stats2[bg * 2 + 1], sh[4] + sh[5] + sh[6] + sh[7]);
  }
}

__global__ __launch_bounds__(64) void gn_finalize(const float* __restrict__ stats2,
                                                  float* __restrict__ stats) {
  int t = threadIdx.x;  // 64 groups total (2 batches x 32)
  float s = stats2[t * 2], ss = stats2[t * 2 + 1];
  float mean = s * (1.f / 65536.f);
  float var = ss * (1.f / 65536.f) - mean * mean;
  stats[t * 2] = mean;
  stats[t * 2 + 1] = rsqrtf(var + 1e-6f);
}

// ---------------- GN apply + transpose: x (b,c,n) -> hnT (b,n,c) bf16 ----------------
__global__ __launch_bounds__(256) void gn_apply(
    const float* __restrict__ x, const float* __restrict__ gamma,
    const float* __restrict__ beta, const float* __restrict__ stats,
    ushort_t* __restrict__ hnT) {
  __shared__ float T[32][33];
  int i0 = blockIdx.x * 32, c0 = blockIdx.y * 32, b = blockIdx.z;
  int tx = threadIdx.x, ty = threadIdx.y;  // (32,8)
#pragma unroll
  for (int k = 0; k < 4; k++) {
    int cl = ty + k * 8;
    int c = c0 + cl;
    int bg = (b * 32 + (c >> 4)) * 2;
    float mean = stats[bg], rstd = stats[bg + 1];
    float v = x[((size_t)(b * 512 + c)) * 4096 + i0 + tx];
    T[cl][tx] = (v - mean) * rstd * gamma[c] + beta[c];
  }
  __syncthreads();
#pragma unroll
  for (int k = 0; k < 4; k++) {
    int il = ty + k * 8;
    hnT[((size_t)b * 4096 + i0 + il) * 512 + c0 + tx] = f2bf(T[tx][il]);
  }
}

// ---------------- bf16 C = A * B^T GEMM, 128 x BN tile (round-5 engine) -------
// omode: 0 = bf16 out, 1 = fp32 + residual, 2 = fp8 e4m3 out.
template <int BN>
__global__ __launch_bounds__(256) void gemm_abt(
    const ushort_t* __restrict__ A, long long sA, int lda,
    const ushort_t* __restrict__ B, long long sB, int ldb,
    int K, int N, int ldc,
    ushort_t* __restrict__ outB, long long sC,
    const float* __restrict__ bias, int bias_mode, float scale,
    float* __restrict__ outF, const float* __restrict__ resid,
    float* __restrict__ rowsum, const float* __restrict__ colscale,
    int swiz, int omode) {
  constexpr int CPW = (8 + BN / 16) / 4;
  constexpr int SB = (128 + BN) * 32;      // halfwords per LDS buffer
  constexpr int MI = (BN == 128) ? 4 : 2;
  constexpr int NI = 4;
  __shared__ __align__(16) ushort_t Ls[2][SB];

  int bx = blockIdx.x, by = blockIdx.y, bz = blockIdx.z;
  if (swiz) {
    unsigned nx = gridDim.x, ny = gridDim.y;
    unsigned id = (blockIdx.z * ny + blockIdx.y) * nx + blockIdx.x;
    unsigned pb8 = (nx * ny) >> 3;
    unsigned c = id & 7, j = id >> 3;
    bz = j / pb8;
    unsigned jb = j - bz * pb8;
    unsigned jy = jb / nx;
    by = c * (ny >> 3) + jy;
    bx = jb - jy * nx;
  }

  int m0 = by * 128, n0 = bx * BN;
  int t = threadIdx.x;
  int lane = t & 63;
  int quad = lane >> 4, l16 = lane & 15;
  int wave = t >> 6;
  int wm = (BN == 128) ? (wave >> 1) * 64 : wave * 32;
  int wn = (BN == 128) ? (wave & 1) * 64 : 0;

  f32x4 acc[MI][NI];
#pragma unroll
  for (int i = 0; i < MI; i++)
#pragma unroll
    for (int j = 0; j < NI; j++)
#pragma unroll
      for (int r = 0; r < 4; r++) acc[i][j][r] = 0.f;

  const ushort_t* gp[CPW];
  int lofs[CPW];
  int crow = lane >> 2, skoff = (lane & 3) * 8;
#pragma unroll
  for (int i = 0; i < CPW; i++) {
    int c = wave * CPW + i;
    if (c < 8) {
      gp[i] = A + (size_t)bz * sA + (size_t)(m0 + c * 16 + crow) * lda + skoff;
      lofs[i] = c * 1024 + lane * 16;
    } else {
      int slot = (c - 8) * 16 + crow;
      int arow = (slot & ~63) + ((slot & 15) * 4) + ((slot & 63) >> 4);
      gp[i] = B + (size_t)bz * sB + (size_t)(n0 + arow) * ldb + skoff;
      lofs[i] = 8192 + (c - 8) * 1024 + lane * 16;
    }
  }
  char* lbase = (char*)&Ls[0][0];

#pragma unroll
  for (int i = 0; i < CPW; i++) gload16(gp[i], lbase + lofs[i]);

  for (int k0 = 0; k0 < K; k0 += 32) {
    int p = (k0 >> 5) & 1;
    __syncthreads();
    if (k0 + 32 < K) {
      int pofs = (p ^ 1) * (SB * 2);
#pragma unroll
      for (int i = 0; i < CPW; i++) gload16(gp[i] + k0 + 32, lbase + pofs + lofs[i]);
    }
    bf16x8 af[MI], bfr[NI];
#pragma unroll
    for (int i = 0; i < MI; i++)
      af[i] = *(const bf16x8*)&Ls[p][(wm + i * 16 + l16) * 32 + quad * 8];
#pragma unroll
    for (int j = 0; j < NI; j++)
      bfr[j] = *(const bf16x8*)&Ls[p][4096 + (wn + j * 16 + l16) * 32 + quad * 8];
#pragma unroll
    for (int mi = 0; mi < MI; mi++)
#pragma unroll
      for (int ni = 0; ni < NI; ni++)
        acc[mi][ni] = __builtin_amdgcn_mfma_f32_16x16x32_bf16(af[mi], bfr[ni], acc[mi][ni], 0, 0, 0);
  }

  size_t cbase = (size_t)bz * sC;
  int gnb = n0 + wn + l16 * 4;
  float cs4[4] = {1.f, 1.f, 1.f, 1.f};
  if (colscale) {
    float4 c4 = *(const float4*)&colscale[(size_t)bz * N + gnb];
    cs4[0] = 1.f / c4.x; cs4[1] = 1.f / c4.y; cs4[2] = 1.f / c4.z; cs4[3] = 1.f / c4.w;
  }
  float b4[4] = {0.f, 0.f, 0.f, 0.f};
  if (bias_mode == 2) {
    float4 t4 = *(const float4*)&bias[gnb];
    b4[0] = t4.x; b4[1] = t4.y; b4[2] = t4.z; b4[3] = t4.w;
  }
#pragma unroll
  for (int mi = 0; mi < MI; mi++) {
#pragma unroll
    for (int r = 0; r < 4; r++) {
      int m = m0 + wm + mi * 16 + quad * 4 + r;
      float rbias = (bias_mode == 1) ? bias[m] : 0.f;
      float v4[4];
      float rs = 0.f;
#pragma unroll
      for (int ni = 0; ni < NI; ni++) {
        float val = acc[mi][ni][r];
        if (colscale) val *= cs4[ni];
        val += (bias_mode == 2) ? b4[ni] : rbias;
        val *= scale;
        if (rowsum) { val = __expf(val) * 0.0625f; rs += val; }
        v4[ni] = val;
      }
      size_t idx = cbase + (size_t)m * ldc + gnb;
      if (omode == 1) {
        float4 rv = *(const float4*)&resid[idx];
        float4 ov = make_float4(v4[0] + rv.x, v4[1] + rv.y, v4[2] + rv.z, v4[3] + rv.w);
        *(float4*)&outF[idx] = ov;
      } else if (omode == 2) {
        unsigned w = __builtin_amdgcn_cvt_pk_fp8_f32(v4[0], v4[1], 0u, false);
        w = __builtin_amdgcn_cvt_pk_fp8_f32(v4[2], v4[3], w, true);
        *(unsigned*)&((uchar_t*)outB)[idx] = w;
      } else {
        unsigned lo = (unsigned)f2bf(v4[0]) | ((unsigned)f2bf(v4[1]) << 16);
        unsigned hi = (unsigned)f2bf(v4[2]) | ((unsigned)f2bf(v4[3]) << 16);
        *(uint2*)&outB[idx] = make_uint2(lo, hi);
      }
      if (rowsum) {
        rs += __shfl_xor(rs, 1, 64);
        rs += __shfl_xor(rs, 2, 64);
        rs += __shfl_xor(rs, 4, 64);
        rs += __shfl_xor(rs, 8, 64);
        if (l16 == 0) atomicAdd(&rowsum[(size_t)bz * 4096 + m], rs);
      }
    }
  }
}

// ---------------- fp8 C = A * B^T GEMM, 128 x BN tile, BK=64 ------------------
// SEG-TRANSPOSED staging: lane i stages (row i&15, 16B-seg i>>4) so LDS slot
// (r,s) = chunk*1024 + r*16 + s*256. Fragment b64 reads then hit banks
// 4*(l16%8)+2*(quad&1)+{0,1}: 32 banks, 2 lanes/bank = conflict-free (m136).
// omode 0: bf16 out. omode 2: exp(scale*acc)/16 -> fp8 out + rowsum.
template <int BN>
__global__ __launch_bounds__(256) void gemm_fp8(
    const uchar_t* __restrict__ A, long long sA, int lda,
    const uchar_t* __restrict__ B, long long sB, int ldb,
    int K, int ldc,
    void* __restrict__ outp, long long sC,
    float scale, float* __restrict__ rowsum, int swiz, int omode) {
  constexpr int CPW = (8 + BN / 16) / 4;
  constexpr int SBB = (128 + BN) * 64;   // bytes per buffer
  constexpr int MI = (BN == 128) ? 4 : 2;
  constexpr int NI = 4;
  __shared__ __align__(16) uchar_t Ls[2][SBB];

  int bx = blockIdx.x, by = blockIdx.y, bz = blockIdx.z;
  if (swiz) {
    unsigned nx = gridDim.x, ny = gridDim.y;
    unsigned id = (blockIdx.z * ny + blockIdx.y) * nx + blockIdx.x;
    unsigned pb8 = (nx * ny) >> 3;
    unsigned c = id & 7, j = id >> 3;
    bz = j / pb8;
    unsigned jb = j - bz * pb8;
    unsigned jy = jb / nx;
    by = c * (ny >> 3) + jy;
    bx = jb - jy * nx;
  }

  int m0 = by * 128, n0 = bx * BN;
  int t = threadIdx.x;
  int lane = t & 63;
  int quad = lane >> 4, l16 = lane & 15;
  int wave = t >> 6;
  int wm = (BN == 128) ? (wave >> 1) * 64 : wave * 32;
  int wn = (BN == 128) ? (wave & 1) * 64 : 0;

  f32x4 acc[MI][NI];
#pragma unroll
  for (int i = 0; i < MI; i++)
#pragma unroll
    for (int j = 0; j < NI; j++)
#pragma unroll
      for (int r = 0; r < 4; r++) acc[i][j][r] = 0.f;

  // seg-transposed staging map
  const uchar_t* gp[CPW];
  int lofs[CPW];
  int r16 = lane & 15, sseg = (lane >> 4) * 16;
#pragma unroll
  for (int i = 0; i < CPW; i++) {
    int c = wave * CPW + i;
    if (c < 8) {
      gp[i] = A + (size_t)bz * sA + (size_t)(m0 + c * 16 + r16) * lda + sseg;
      lofs[i] = c * 1024 + lane * 16;
    } else {
      int slot = (c - 8) * 16 + r16;
      int arow = (slot & ~63) + ((slot & 15) * 4) + ((slot & 63) >> 4);
      gp[i] = B + (size_t)bz * sB + (size_t)(n0 + arow) * ldb + sseg;
      lofs[i] = 8192 + (c - 8) * 1024 + lane * 16;
    }
  }
  char* lbase = (char*)&Ls[0][0];

#pragma unroll
  for (int i = 0; i < CPW; i++) gload16(gp[i], lbase + lofs[i]);

  int vbase = l16 * 16 + (quad >> 1) * 256 + (quad & 1) * 8;
  for (int k0 = 0; k0 < K; k0 += 64) {
    int p = (k0 >> 6) & 1;
    __syncthreads();
    if (k0 + 64 < K) {
      int pofs = (p ^ 1) * SBB;
#pragma unroll
      for (int i = 0; i < CPW; i++) gload16(gp[i] + k0 + 64, lbase + pofs + lofs[i]);
    }
    const uchar_t* Lp = &Ls[p][0];
    long long af[2][MI], bfv[2][NI];
#pragma unroll
    for (int s = 0; s < 2; s++) {
#pragma unroll
      for (int i = 0; i < MI; i++)
        af[s][i] = *(const long long*)&Lp[wm * 64 + i * 1024 + s * 512 + vbase];
#pragma unroll
      for (int j = 0; j < NI; j++)
        bfv[s][j] = *(const long long*)&Lp[8192 + wn * 64 + j * 1024 + s * 512 + vbase];
    }
#pragma unroll
    for (int s = 0; s < 2; s++)
#pragma unroll
      for (int mi = 0; mi < MI; mi++)
#pragma unroll
        for (int ni = 0; ni < NI; ni++)
          acc[mi][ni] = __builtin_amdgcn_mfma_f32_16x16x32_fp8_fp8(af[s][mi], bfv[s][ni], acc[mi][ni], 0, 0, 0);
  }

  size_t cbase = (size_t)bz * sC;
  int gnb = n0 + wn + l16 * 4;
#pragma unroll
  for (int mi = 0; mi < MI; mi++) {
#pragma unroll
    for (int r = 0; r < 4; r++) {
      int m = m0 + wm + mi * 16 + quad * 4 + r;
      if (omode == 2) {
        float v4[4];
        float rs = 0.f;
#pragma unroll
        for (int ni = 0; ni < NI; ni++) {
          v4[ni] = __expf(acc[mi][ni][r] * scale) * 0.0625f;
          rs += v4[ni];
        }
        unsigned w = __builtin_amdgcn_cvt_pk_fp8_f32(v4[0], v4[1], 0u, false);
        w = __builtin_amdgcn_cvt_pk_fp8_f32(v4[2], v4[3], w, true);
        *(unsigned*)&((uchar_t*)outp)[cbase + (size_t)m * ldc + gnb] = w;
        rs += __shfl_xor(rs, 1, 64);
        rs += __shfl_xor(rs, 2, 64);
        rs += __shfl_xor(rs, 4, 64);
        rs += __shfl_xor(rs, 8, 64);
        if (l16 == 0) atomicAdd(&rowsum[(size_t)bz * 4096 + m], rs);
      } else {
        unsigned lo = (unsigned)f2bf(acc[mi][0][r]) | ((unsigned)f2bf(acc[mi][1][r]) << 16);
        unsigned hi = (unsigned)f2bf(acc[mi][2][r]) | ((unsigned)f2bf(acc[mi][3][r]) << 16);
        *(uint2*)&((ushort_t*)outp)[cbase + (size_t)m * ldc + gnb] = make_uint2(lo, hi);
      }
    }
  }
}

extern "C" void kernel_launch(void* const* d_in, const int* in_sizes, int n_in,
                              void* d_out, int out_size, void* d_ws, size_t ws_size,
                              hipStream_t stream) {
  const float* x     = (const float*)d_in[0];
  const float* gamma = (const float*)d_in[1];
  const float* beta  = (const float*)d_in[2];
  const float* wq    = (const float*)d_in[3];
  const float* bq    = (const float*)d_in[4];
  const float* wk    = (const float*)d_in[5];
  const float* bk    = (const float*)d_in[6];
  const float* wv    = (const float*)d_in[7];
  const float* bv    = (const float*)d_in[8];
  const float* wo    = (const float*)d_in[9];
  const float* bo    = (const float*)d_in[10];
  float* out = (float*)d_out;

  // workspace layout
  ushort_t* wb  = (ushort_t*)d_ws;     // [wq;wk] 1024x512, wv, wo (bf16)
  ushort_t* wvb = wb + 524288;
  ushort_t* wob = wb + 786432;
  ushort_t* hnT = wb + 1048576;        // 2 x 4096 x 512 bf16
  uchar_t*  qk8 = (uchar_t*)(hnT + 4194304);  // 2 x 4096 x 1024 fp8 (q | k)
  uchar_t*  vC8 = qk8 + 8388608;       // 2 x 512 x 4096 fp8
  ushort_t* OT  = (ushort_t*)(vC8 + 4194304); // 2 x 4096 x 512 bf16
  uchar_t*  S8  = (uchar_t*)(OT + 4194304);   // 2 x 4096 x 4096 fp8 (P' = exp/16)
  float* fbuf   = (float*)(S8 + 33554432);
  float* stats  = fbuf;                // 128
  float* stats2 = fbuf + 128;          // 128
  float* qkbias = fbuf + 256;          // 1024
  float* l      = (float*)hnT;         // 2 x 4096 row sums (hnT dead after v-GEMM)

  const long long HS = 2097152;   // 4096*512 per batch
  const long long QS = 4194304;   // 4096*1024 per batch (bytes, fp8)
  const long long SS = 16777216;  // 4096*4096 per batch (bytes, fp8)
  const float scale = 0.044194173824159216f;  // 512^-0.5

  cvt_weights<<<dim3(1029), dim3(256), 0, stream>>>(wq, wk, wv, wo, bq, bk, wb, qkbias, stats2);
  gn_stats_partial<<<dim3(256), dim3(256), 0, stream>>>(x, stats2);
  gn_finalize<<<dim3(1), dim3(64), 0, stream>>>(stats2, stats);
  gn_apply<<<dim3(128, 16, 2), dim3(32, 8), 0, stream>>>(x, gamma, beta, stats, hnT);
  // qk8 = hnT * [wq;wk]^T (M=4096, N=1024, K=512), packed col bias, fp8 out, unscaled
  gemm_abt<128><<<dim3(8, 32, 2), dim3(256), 0, stream>>>(
      hnT, HS, 512, wb, 0, 512, 512, 1024, 1024, (ushort_t*)qk8, QS, qkbias, 2, 1.f,
      nullptr, nullptr, nullptr, nullptr, 1, 2);
  // vC8 = wv * hnT^T (M=512, N=4096, K=512), row bias, fp8 out
  gemm_abt<64><<<dim3(64, 4, 2), dim3(256), 0, stream>>>(
      wvb, 0, 512, hnT, HS, 512, 512, 4096, 4096, (ushort_t*)vC8, HS, bv, 1, 1.f,
      nullptr, nullptr, nullptr, nullptr, 0, 2);
  // hnT dead; reuse as rowsum l
  zero_f32<<<dim3(32), dim3(256), 0, stream>>>(l);
  // P' = exp(scale * q*k^T)/16 fp8 + fused row sums (fp8 MFMA, M=N=4096, K=512)
  gemm_fp8<128><<<dim3(32, 32, 2), dim3(256), 0, stream>>>(
      qk8, QS, 1024, qk8 + 512, QS, 1024, 512, 4096, S8, SS, scale, l, 1, 2);
  // OT = P' * vC8^T (fp8 MFMA, M=4096, N=512, K=4096), bf16 out, swizzled
  gemm_fp8<64><<<dim3(8, 32, 2), dim3(256), 0, stream>>>(
      S8, SS, 4096, vC8, HS, 4096, 4096, 512, OT, HS, 1.f, nullptr, 1, 0);
  // y = wo * (OT/l')^T + bo + x (M=512, N=4096, K=512), fp32 + residual
  gemm_abt<64><<<dim3(64, 4, 2), dim3(256), 0, stream>>>(
      wob, 0, 512, OT, HS, 512, 512, 4096, 4096, nullptr, HS, bo, 1, 1.f,
      out, x, nullptr, l, 0, 1);
}